// Round 5
// baseline (82.494 us; speedup 1.0000x reference)
//
#include <hip/hip_runtime.h>
#include <math.h>

// Problem constants (match reference)
#define T_TOTAL 8192
#define KK      10
#define DMODEL  256
#define BATCH   32
#define D4      (DMODEL/4)                   // 64 float4 per row
#define PE4     (T_TOTAL * D4)               // 524288 float4 per batch
#define TOT4    ((size_t)BATCH * PE4)        // 16,777,216 float4 total
#define JPT     16                           // float4 per thread
#define CHUNK4  (256 * JPT)                  // 4096 float4 = 64 KB per block
#define ROWS_PB 64                           // t-rows per block (CHUNK4 / D4)

typedef float f32x4 __attribute__((ext_vector_type(4)));

// One block = one contiguous 64 KB chunk of the flat [B,T,D] tensor
// (= 64 consecutive t-rows of one batch). Fill-like linear address streams,
// 16 outstanding loads per thread.
__global__ __launch_bounds__(256) void gre_stream_fused(
    const f32x4* __restrict__ x4,
    const float* __restrict__ emb,
    const float* __restrict__ mu,
    const float* __restrict__ sigma,
    f32x4* __restrict__ o4)
{
    const int tid = threadIdx.x;
    const size_t base = (size_t)blockIdx.x * CHUNK4 + tid;

    // Phase 1: issue all 16 x loads immediately (contiguous 64 KB block span)
    f32x4 v[JPT];
#pragma unroll
    for (int j = 0; j < JPT; ++j)
        v[j] = x4[base + (size_t)j * 256];

    // Cooperative softmax weights for this block's 64 rows -> LDS.
    // Row r handled (redundantly) by the 4 threads with tid>>2 == r.
    __shared__ float wsm[ROWS_PB][KK];
    {
        const int r = tid >> 2;                       // 0..63
        const int t = ((blockIdx.x * ROWS_PB) & (T_TOTAL - 1)) + r;
        float lp[KK];
        float mx = -INFINITY;
#pragma unroll
        for (int k = 0; k < KK; ++k) {
            const float mk = mu[k];
            const float sk = sigma[k];
            const float a  = (float)t - mk;
            const float val = -(a * a) / (2.0f * sk + 1e-8f)
                              - 0.5f * __logf(fabsf(sk) + 1e-8f);
            lp[k] = val;
            mx = fmaxf(mx, val);
        }
        float s = 0.0f;
#pragma unroll
        for (int k = 0; k < KK; ++k) { lp[k] = __expf(lp[k] - mx); s += lp[k]; }
        const float inv = 1.0f / s;
        // 4 threads per row; k split {k0, k0+4} + first two add {8,9}
        const int k0 = tid & 3;
        wsm[r][k0]     = lp[k0] * inv;
        wsm[r][k0 + 4] = lp[k0 + 4] * inv;
        if (k0 < 2) wsm[r][8 + k0] = lp[8 + k0] * inv;
    }

    // emb columns for this thread's column c -> registers (tiny, L1/L2-hot)
    const int c = tid & 63;
    const f32x4* __restrict__ emb4 = (const f32x4*)emb;
    f32x4 e[KK];
#pragma unroll
    for (int k = 0; k < KK; ++k)
        e[k] = emb4[k * D4 + c];

    __syncthreads();  // wsm ready

    // Phase 2: pe from LDS-broadcast weights + register emb, add, nt store.
    // Row for element j: (tid>>6) + 4*j  (same for all lanes of a wave -> broadcast)
#pragma unroll
    for (int j = 0; j < JPT; ++j) {
        const int r = (tid >> 6) + 4 * j;
        f32x4 pe = (f32x4){0.f, 0.f, 0.f, 0.f};
#pragma unroll
        for (int k = 0; k < KK; ++k)
            pe += wsm[r][k] * e[k];
        f32x4 res = v[j] + pe;
        __builtin_nontemporal_store(res, &o4[base + (size_t)j * 256]);
    }
}

extern "C" void kernel_launch(void* const* d_in, const int* in_sizes, int n_in,
                              void* d_out, int out_size, void* d_ws, size_t ws_size,
                              hipStream_t stream) {
    const float* x     = (const float*)d_in[0];
    const float* emb   = (const float*)d_in[1];
    const float* mu    = (const float*)d_in[2];
    const float* sigma = (const float*)d_in[3];
    float* out         = (float*)d_out;

    const int blocks = (int)(TOT4 / CHUNK4);  // 4096
    gre_stream_fused<<<blocks, 256, 0, stream>>>(
        (const f32x4*)x, emb, mu, sigma, (f32x4*)out);
}